// Round 2
// baseline (428.694 us; speedup 1.0000x reference)
//
#include <hip/hip_runtime.h>
#include <hip/hip_bf16.h>
#include <stdint.h>

#define B_ROWS 32768
#define HID    2048
#define K_DIM  2048

#define BM 256
#define BN 128
#define BK 64   // 4 k16-steps per staged tile; LDS = 32KB(A) + 16KB(B)

typedef __bf16 bf16x8_t  __attribute__((ext_vector_type(8)));
typedef float  f32x16_t  __attribute__((ext_vector_type(16)));

// tanh via v_exp + v_rcp: ~6 VALU ops, abs err ~1e-7 (negligible vs bf16 budget).
__device__ __forceinline__ float fast_tanh(float x) {
    float e = __expf(2.0f * x);
    return 1.0f - 2.0f * __builtin_amdgcn_rcpf(e + 1.0f);
}

// async global->LDS, 16B/lane. LDS dest is wave-uniform base + lane*16.
__device__ __forceinline__ void gl_lds16(const void* g, void* l) {
    __builtin_amdgcn_global_load_lds(
        (const __attribute__((address_space(1))) void*)(uintptr_t)g,
        (__attribute__((address_space(3))) void*)(uint32_t)(uintptr_t)l,
        16, 0, 0);
}

// ---------------- kernel 1: W2 [K,N] fp32 -> W2t [N,K] bf16 ----------------
__global__ __launch_bounds__(256) void transpose_w2_kernel(
    const float* __restrict__ W2, __bf16* __restrict__ W2t) {
    __shared__ float tile[32][33];
    const int n0 = blockIdx.x * 32;
    const int k0 = blockIdx.y * 32;
    const int tx = threadIdx.x;              // 0..31
    const int ty = threadIdx.y;              // 0..7
#pragma unroll
    for (int i = 0; i < 4; ++i) {
        int k = k0 + ty + i * 8;
        tile[ty + i * 8][tx] = W2[(size_t)k * HID + n0 + tx];
    }
    __syncthreads();
#pragma unroll
    for (int i = 0; i < 4; ++i) {
        int n = n0 + ty + i * 8;
        W2t[(size_t)n * K_DIM + k0 + tx] = (__bf16)tile[tx][ty + i * 8];
    }
}

// ------- kernel 2: layer1 (6-feature GEMV) -> h1 bf16; regressor; logit init -------
__global__ __launch_bounds__(256) void layer1_kernel(
    const float* __restrict__ x,   const float* __restrict__ W1, const float* __restrict__ b1,
    const float* __restrict__ Wr1, const float* __restrict__ br1,
    const float* __restrict__ Wr2, const float* __restrict__ br2,
    const float* __restrict__ Wr3, const float* __restrict__ br3,
    const float* __restrict__ bc,
    __bf16* __restrict__ h1, float* __restrict__ out) {
    const int t  = threadIdx.x;
    const int n0 = t * 8;
    float w0[8], w1[8], w2[8], w3[8], wb[8];
#pragma unroll
    for (int j = 0; j < 8; ++j) {
        w0[j] = W1[0 * HID + n0 + j];
        w1[j] = W1[1 * HID + n0 + j];
        w2[j] = W1[2 * HID + n0 + j];
        w3[j] = W1[3 * HID + n0 + j];
        // qfeat[2]=qfeat[3]=1 always (cos(0) on padded wires) -> fold into bias
        wb[j] = W1[4 * HID + n0 + j] + W1[5 * HID + n0 + j] + b1[n0 + j];
    }
    const int brow0 = blockIdx.x * 8;
#pragma unroll
    for (int r = 0; r < 8; ++r) {
        const int b = brow0 + r;
        const float x0 = x[2 * b], x1 = x[2 * b + 1];
        const float c0 = cosf(x0);
        const float cc = c0 * cosf(x1);
        bf16x8_t v;
#pragma unroll
        for (int j = 0; j < 8; ++j) {
            float z = wb[j] + x0 * w0[j] + x1 * w1[j] + c0 * w2[j] + cc * w3[j];
            v[j] = (__bf16)fast_tanh(z);
        }
        *(bf16x8_t*)(h1 + (size_t)b * HID + n0) = v;
    }
    if (t < 8) {
        const int b = brow0 + t;
        const float x0 = x[2 * b], x1 = x[2 * b + 1];
        float r1[8];
#pragma unroll
        for (int j = 0; j < 8; ++j)
            r1[j] = fast_tanh(br1[j] + x0 * Wr1[j] + x1 * Wr1[8 + j]);
        float r2[4];
#pragma unroll
        for (int j = 0; j < 4; ++j) {
            float s = br2[j];
#pragma unroll
            for (int i = 0; i < 8; ++i) s += r1[i] * Wr2[i * 4 + j];
            r2[j] = fast_tanh(s);
        }
        float risk = br3[0];
#pragma unroll
        for (int i = 0; i < 4; ++i) risk += r2[i] * Wr3[i];
        out[B_ROWS + b] = risk;
        out[b]          = bc[0];
    }
}

// ------- kernel 3: h1 @ W2t^T -> tanh(+b2) -> dot Wc -> atomic logits -------
// 256x128 block tile, 4 waves, wave tile 128x64 = 4x2 of mfma_f32_32x32x16_bf16.
// LDS-traffic-optimized: 6 fragment reads per 8 MFMAs (23.4 B/kFLOP vs 31.25 for
// the 16x16 4x4 scheme). XOR chunk swizzle keeps ds_read_b128 conflict-free.
__global__ __launch_bounds__(256, 2) void gemm_kernel(
    const __bf16* __restrict__ A,   // h1  [32768, 2048]
    const __bf16* __restrict__ Bt,  // W2t [2048, 2048]
    const float* __restrict__ b2, const float* __restrict__ Wc,
    float* __restrict__ out) {
    __shared__ __align__(16) unsigned short sA[BM * BK];  // 32 KB
    __shared__ __align__(16) unsigned short sB[BN * BK];  // 16 KB

    const int tid  = threadIdx.x;
    const int wave = tid >> 6;
    const int lane = tid & 63;
    const int bid  = blockIdx.x;
    const int m0 = (bid >> 4) * BM;   // 128 m-tiles; 16 consecutive blocks share A slab
    const int n0 = (bid & 15) * BN;   // 16 n-tiles

    // staging: 1KB per gl_lds16 call (8 rows x 8 chunks of 16B).
    // lane l -> row l/8, LDS slot l%8; global chunk = (l%8)^(l/8)  [swizzle]
    const char* aSrc[8]; char* aDst[8];
    const char* bSrc[4]; char* bDst[4];
    {
        const int rsub  = lane >> 3;
        const int chunk = (lane & 7) ^ rsub;
#pragma unroll
        for (int i = 0; i < 8; ++i) {
            int seg = wave * 8 + i;
            aSrc[i] = (const char*)A + (size_t)(m0 + seg * 8 + rsub) * (K_DIM * 2) + chunk * 16;
            aDst[i] = (char*)sA + seg * 1024;
        }
#pragma unroll
        for (int i = 0; i < 4; ++i) {
            int seg = wave * 4 + i;
            bSrc[i] = (const char*)Bt + (size_t)(n0 + seg * 8 + rsub) * (K_DIM * 2) + chunk * 16;
            bDst[i] = (char*)sB + seg * 1024;
        }
    }

    f32x16_t acc[4][2] = {};
    const int mw    = (wave & 1) * 128;
    const int nw    = (wave >> 1) * 64;
    const int l31   = lane & 31;
    const int khalf = lane >> 5;       // which k-half of 16 the lane holds
    const int x7    = lane & 7;

    for (int kb = 0; kb < K_DIM * 2; kb += BK * 2) {
#pragma unroll
        for (int i = 0; i < 8; ++i) gl_lds16(aSrc[i] + kb, aDst[i]);
#pragma unroll
        for (int i = 0; i < 4; ++i) gl_lds16(bSrc[i] + kb, bDst[i]);
        __syncthreads();
#pragma unroll
        for (int kk = 0; kk < 4; ++kk) {
            const int slot = ((kk * 2 + khalf) ^ x7) * 16;   // un-swizzled byte offset
            bf16x8_t af[4], bfr[2];
#pragma unroll
            for (int mi = 0; mi < 4; ++mi)
                af[mi]  = *(const bf16x8_t*)((const char*)sA + (mw + mi * 32 + l31) * 128 + slot);
#pragma unroll
            for (int ni = 0; ni < 2; ++ni)
                bfr[ni] = *(const bf16x8_t*)((const char*)sB + (nw + ni * 32 + l31) * 128 + slot);
#pragma unroll
            for (int mi = 0; mi < 4; ++mi)
#pragma unroll
                for (int ni = 0; ni < 2; ++ni)
                    acc[mi][ni] = __builtin_amdgcn_mfma_f32_32x32x16_bf16(
                        af[mi], bfr[ni], acc[mi][ni], 0, 0, 0);
        }
        __syncthreads();
    }

    // epilogue: h2 = tanh(acc + b2); logits += h2 . Wc  (h2 never hits memory)
    // C/D layout (m74/m101-verified): col = lane&31, row = (reg&3) + 8*(reg>>2) + 4*(lane>>5)
    float b2v[2], wcv[2];
#pragma unroll
    for (int ni = 0; ni < 2; ++ni) {
        int gn = n0 + nw + ni * 32 + l31;
        b2v[ni] = b2[gn];
        wcv[ni] = Wc[gn];
    }
#pragma unroll
    for (int mi = 0; mi < 4; ++mi) {
#pragma unroll
        for (int reg = 0; reg < 16; ++reg) {
            int gm = m0 + mw + mi * 32 + (reg & 3) + 8 * (reg >> 2) + 4 * khalf;
            float rs = 0.f;
#pragma unroll
            for (int ni = 0; ni < 2; ++ni)
                rs += fast_tanh(acc[mi][ni][reg] + b2v[ni]) * wcv[ni];
            rs += __shfl_xor(rs, 1);
            rs += __shfl_xor(rs, 2);
            rs += __shfl_xor(rs, 4);
            rs += __shfl_xor(rs, 8);
            rs += __shfl_xor(rs, 16);  // reduce the 32 cols this half-wave holds
            if (l31 == 0) atomicAdd(&out[gm], rs);  // 32 atomics/row total
        }
    }
}

extern "C" void kernel_launch(void* const* d_in, const int* in_sizes, int n_in,
                              void* d_out, int out_size, void* d_ws, size_t ws_size,
                              hipStream_t stream) {
    const float* x   = (const float*)d_in[0];
    const float* W1  = (const float*)d_in[1];
    const float* b1  = (const float*)d_in[2];
    const float* W2  = (const float*)d_in[3];
    const float* b2  = (const float*)d_in[4];
    const float* Wc  = (const float*)d_in[5];
    const float* bc  = (const float*)d_in[6];
    const float* Wr1 = (const float*)d_in[7];
    const float* br1 = (const float*)d_in[8];
    const float* Wr2 = (const float*)d_in[9];
    const float* br2 = (const float*)d_in[10];
    const float* Wr3 = (const float*)d_in[11];
    const float* br3 = (const float*)d_in[12];
    float* out = (float*)d_out;

    // ws layout: [0,8MB) W2t bf16 [N,K]; [8MB, 8MB+128MB) h1 bf16 [B,H]
    __bf16* W2t = (__bf16*)d_ws;
    __bf16* h1  = (__bf16*)((char*)d_ws + (size_t)8 * 1024 * 1024);

    transpose_w2_kernel<<<dim3(HID / 32, K_DIM / 32), dim3(32, 8), 0, stream>>>(W2, W2t);
    layer1_kernel<<<B_ROWS / 8, 256, 0, stream>>>(x, W1, b1, Wr1, br1, Wr2, br2,
                                                  Wr3, br3, bc, h1, out);
    gemm_kernel<<<(B_ROWS / BM) * (HID / BN), 256, 0, stream>>>(h1, W2t, b2, Wc, out);
}

// Round 3
// 361.407 us; speedup vs baseline: 1.1862x; 1.1862x over previous
//
#include <hip/hip_runtime.h>
#include <hip/hip_bf16.h>
#include <stdint.h>

#define B_ROWS 32768
#define HID    2048
#define K_DIM  2048

#define BM 128
#define BN 256
#define BK 64   // 2 MFMA k-steps (16x16x32) per staged tile; LDS = 16KB(A)+32KB(B)

typedef __bf16 bf16x8_t __attribute__((ext_vector_type(8)));
typedef float  f32x4_t  __attribute__((ext_vector_type(4)));

// tanh via v_exp + v_rcp: ~6 VALU ops, abs err ~1e-7 (negligible vs bf16 budget).
__device__ __forceinline__ float fast_tanh(float x) {
    float e = __expf(2.0f * x);
    return 1.0f - 2.0f * __builtin_amdgcn_rcpf(e + 1.0f);
}

// async global->LDS, 16B/lane. LDS dest is wave-uniform base + lane*16.
__device__ __forceinline__ void gl_lds16(const void* g, void* l) {
    __builtin_amdgcn_global_load_lds(
        (const __attribute__((address_space(1))) void*)(uintptr_t)g,
        (__attribute__((address_space(3))) void*)(uint32_t)(uintptr_t)l,
        16, 0, 0);
}

// ---------------- kernel 1: W2 [K,N] fp32 -> W2t [N,K] bf16 ----------------
__global__ __launch_bounds__(256) void transpose_w2_kernel(
    const float* __restrict__ W2, __bf16* __restrict__ W2t) {
    __shared__ float tile[32][33];
    const int n0 = blockIdx.x * 32;
    const int k0 = blockIdx.y * 32;
    const int tx = threadIdx.x;              // 0..31
    const int ty = threadIdx.y;              // 0..7
#pragma unroll
    for (int i = 0; i < 4; ++i) {
        int k = k0 + ty + i * 8;
        tile[ty + i * 8][tx] = W2[(size_t)k * HID + n0 + tx];
    }
    __syncthreads();
#pragma unroll
    for (int i = 0; i < 4; ++i) {
        int n = n0 + ty + i * 8;
        W2t[(size_t)n * K_DIM + k0 + tx] = (__bf16)tile[tx][ty + i * 8];
    }
}

// ------- kernel 2: layer1 (6-feature GEMV) -> h1 bf16; regressor; logit init -------
__global__ __launch_bounds__(256) void layer1_kernel(
    const float* __restrict__ x,   const float* __restrict__ W1, const float* __restrict__ b1,
    const float* __restrict__ Wr1, const float* __restrict__ br1,
    const float* __restrict__ Wr2, const float* __restrict__ br2,
    const float* __restrict__ Wr3, const float* __restrict__ br3,
    const float* __restrict__ bc,
    __bf16* __restrict__ h1, float* __restrict__ out) {
    const int t  = threadIdx.x;
    const int n0 = t * 8;
    float w0[8], w1[8], w2[8], w3[8], wb[8];
#pragma unroll
    for (int j = 0; j < 8; ++j) {
        w0[j] = W1[0 * HID + n0 + j];
        w1[j] = W1[1 * HID + n0 + j];
        w2[j] = W1[2 * HID + n0 + j];
        w3[j] = W1[3 * HID + n0 + j];
        // qfeat[2]=qfeat[3]=1 always (cos(0) on padded wires) -> fold into bias
        wb[j] = W1[4 * HID + n0 + j] + W1[5 * HID + n0 + j] + b1[n0 + j];
    }
    const int brow0 = blockIdx.x * 8;
#pragma unroll
    for (int r = 0; r < 8; ++r) {
        const int b = brow0 + r;
        const float x0 = x[2 * b], x1 = x[2 * b + 1];
        const float c0 = cosf(x0);
        const float cc = c0 * cosf(x1);
        bf16x8_t v;
#pragma unroll
        for (int j = 0; j < 8; ++j) {
            float z = wb[j] + x0 * w0[j] + x1 * w1[j] + c0 * w2[j] + cc * w3[j];
            v[j] = (__bf16)fast_tanh(z);
        }
        *(bf16x8_t*)(h1 + (size_t)b * HID + n0) = v;
    }
    if (t < 8) {
        const int b = brow0 + t;
        const float x0 = x[2 * b], x1 = x[2 * b + 1];
        float r1[8];
#pragma unroll
        for (int j = 0; j < 8; ++j)
            r1[j] = fast_tanh(br1[j] + x0 * Wr1[j] + x1 * Wr1[8 + j]);
        float r2[4];
#pragma unroll
        for (int j = 0; j < 4; ++j) {
            float s = br2[j];
#pragma unroll
            for (int i = 0; i < 8; ++i) s += r1[i] * Wr2[i * 4 + j];
            r2[j] = fast_tanh(s);
        }
        float risk = br3[0];
#pragma unroll
        for (int i = 0; i < 4; ++i) risk += r2[i] * Wr3[i];
        out[B_ROWS + b] = risk;
        out[b]          = bc[0];
    }
}

// ------- kernel 3: h1 @ W2t^T -> tanh(+b2) -> dot Wc -> atomic logits -------
// 128x256 block tile, 4 waves, wave tile 64x128 = 4x8 of mfma_f32_16x16x32_bf16.
// Fragment-read lane pattern is byte-identical to the proven conflict-free R1
// pattern (quad-based chunk, r16 rows, XOR x7); only row-base constants differ
// (multiples of 16 rows = 2048B = bank-neutral). LDS traffic: 12KB/524kFLOP
// = 22.9 B/kFLOP vs R1's 31.25 -> LDS pipe 290k cyc/CU < MFMA 318k cyc/CU.
__global__ __launch_bounds__(256, 2) void gemm_kernel(
    const __bf16* __restrict__ A,   // h1  [32768, 2048]
    const __bf16* __restrict__ Bt,  // W2t [2048, 2048]
    const float* __restrict__ b2, const float* __restrict__ Wc,
    float* __restrict__ out) {
    __shared__ __align__(16) unsigned short sA[BM * BK];  // 16 KB
    __shared__ __align__(16) unsigned short sB[BN * BK];  // 32 KB

    const int tid  = threadIdx.x;
    const int wave = tid >> 6;
    const int lane = tid & 63;
    const int bid  = blockIdx.x;
    const int m0 = (bid >> 3) * BM;   // 256 m-tiles; 8 consecutive blocks share A slab
    const int n0 = (bid & 7) * BN;    // 8 n-tiles

    // staging: 1KB per gl_lds16 call (8 rows x 8 chunks of 16B).
    // lane l -> row l/8, LDS slot l%8; global chunk = (l%8)^(l/8)  [swizzle]
    const char* aSrc[4]; char* aDst[4];
    const char* bSrc[8]; char* bDst[8];
    {
        const int rsub  = lane >> 3;
        const int chunk = (lane & 7) ^ rsub;
#pragma unroll
        for (int i = 0; i < 4; ++i) {
            int seg = wave * 4 + i;
            aSrc[i] = (const char*)A + (size_t)(m0 + seg * 8 + rsub) * (K_DIM * 2) + chunk * 16;
            aDst[i] = (char*)sA + seg * 1024;
        }
#pragma unroll
        for (int i = 0; i < 8; ++i) {
            int seg = wave * 8 + i;
            bSrc[i] = (const char*)Bt + (size_t)(n0 + seg * 8 + rsub) * (K_DIM * 2) + chunk * 16;
            bDst[i] = (char*)sB + seg * 1024;
        }
    }

    f32x4_t acc[4][8] = {};
    const int mw   = (wave & 1) * 64;
    const int nw   = (wave >> 1) * 128;
    const int quad = lane >> 4;
    const int r16  = lane & 15;
    const int x7   = lane & 7;

    for (int kb = 0; kb < K_DIM * 2; kb += BK * 2) {
#pragma unroll
        for (int i = 0; i < 4; ++i) gl_lds16(aSrc[i] + kb, aDst[i]);
#pragma unroll
        for (int i = 0; i < 8; ++i) gl_lds16(bSrc[i] + kb, bDst[i]);
        __syncthreads();
#pragma unroll
        for (int ks = 0; ks < 2; ++ks) {
            const int slot = ((ks * 4 + quad) ^ x7) * 8;   // short units (16B chunks)
            bf16x8_t af[4], bfr[8];
#pragma unroll
            for (int mi = 0; mi < 4; ++mi)
                af[mi]  = *(const bf16x8_t*)(sA + (mw + mi * 16 + r16) * BK + slot);
#pragma unroll
            for (int ni = 0; ni < 8; ++ni)
                bfr[ni] = *(const bf16x8_t*)(sB + (nw + ni * 16 + r16) * BK + slot);
#pragma unroll
            for (int mi = 0; mi < 4; ++mi)
#pragma unroll
                for (int ni = 0; ni < 8; ++ni)
                    acc[mi][ni] = __builtin_amdgcn_mfma_f32_16x16x32_bf16(
                        af[mi], bfr[ni], acc[mi][ni], 0, 0, 0);
        }
        __syncthreads();
    }

    // epilogue: h2 = tanh(acc + b2); logits += h2 . Wc  (h2 never hits memory)
    // C/D layout (m89/m91-verified): col = lane&15, row = quad*4 + reg
    float b2v[8], wcv[8];
#pragma unroll
    for (int ni = 0; ni < 8; ++ni) {
        int gn = n0 + nw + ni * 16 + r16;
        b2v[ni] = b2[gn];
        wcv[ni] = Wc[gn];
    }
#pragma unroll
    for (int mi = 0; mi < 4; ++mi) {
#pragma unroll
        for (int r = 0; r < 4; ++r) {
            int gm = m0 + mw + mi * 16 + quad * 4 + r;
            float rs = 0.f;
#pragma unroll
            for (int ni = 0; ni < 8; ++ni)
                rs += fast_tanh(acc[mi][ni][r] + b2v[ni]) * wcv[ni];
            rs += __shfl_xor(rs, 1);
            rs += __shfl_xor(rs, 2);
            rs += __shfl_xor(rs, 4);
            rs += __shfl_xor(rs, 8);   // 16-lane group = this wave's 128 cols for row gm
            if (r16 == 0) atomicAdd(&out[gm], rs);  // 16 atomics/row total
        }
    }
}

extern "C" void kernel_launch(void* const* d_in, const int* in_sizes, int n_in,
                              void* d_out, int out_size, void* d_ws, size_t ws_size,
                              hipStream_t stream) {
    const float* x   = (const float*)d_in[0];
    const float* W1  = (const float*)d_in[1];
    const float* b1  = (const float*)d_in[2];
    const float* W2  = (const float*)d_in[3];
    const float* b2  = (const float*)d_in[4];
    const float* Wc  = (const float*)d_in[5];
    const float* bc  = (const float*)d_in[6];
    const float* Wr1 = (const float*)d_in[7];
    const float* br1 = (const float*)d_in[8];
    const float* Wr2 = (const float*)d_in[9];
    const float* br2 = (const float*)d_in[10];
    const float* Wr3 = (const float*)d_in[11];
    const float* br3 = (const float*)d_in[12];
    float* out = (float*)d_out;

    // ws layout: [0,8MB) W2t bf16 [N,K]; [8MB, 8MB+128MB) h1 bf16 [B,H]
    __bf16* W2t = (__bf16*)d_ws;
    __bf16* h1  = (__bf16*)((char*)d_ws + (size_t)8 * 1024 * 1024);

    transpose_w2_kernel<<<dim3(HID / 32, K_DIM / 32), dim3(32, 8), 0, stream>>>(W2, W2t);
    layer1_kernel<<<B_ROWS / 8, 256, 0, stream>>>(x, W1, b1, Wr1, br1, Wr2, br2,
                                                  Wr3, br3, bc, h1, out);
    gemm_kernel<<<(B_ROWS / BM) * (HID / BN), 256, 0, stream>>>(h1, W2t, b2, Wc, out);
}